// Round 6
// baseline (525.077 us; speedup 1.0000x reference)
//
#include <hip/hip_runtime.h>
#include <hip/hip_bf16.h>

#define NN 8192
#define FF 128

typedef unsigned short ushort_t;
typedef __attribute__((ext_vector_type(4))) float f32x4;
typedef __attribute__((ext_vector_type(4))) int i32x4;
typedef __attribute__((ext_vector_type(8))) short s16x8;
typedef __attribute__((ext_vector_type(2))) unsigned long long u64x2;

__device__ __forceinline__ void block_sync_lds() {
  // wait LDS ops only, do NOT drain vmcnt -> global prefetch survives the barrier
  asm volatile("s_waitcnt lgkmcnt(0)\n\ts_barrier" ::: "memory");
}

// ---------------- Kernel 0: bit-pack adj (256 MB -> 8 MB), pure streaming.
// Bit-plane layout: for each 256-int block b, word (b*4+m) bit l <-> adj[b*256 + l*4 + m].
__global__ __launch_bounds__(256)
void k0_pack(const int* __restrict__ adj, unsigned long long* __restrict__ bits)
{
  const int lane = threadIdx.x & 63;
  const int wid = (blockIdx.x * 256 + threadIdx.x) >> 6;   // 8192 waves
  for (int blk = wid; blk < (NN / 256) * NN; blk += 8192) {
    const i32x4 a = *((const i32x4*)adj + (size_t)blk * 64 + lane);   // 1KB contiguous per wave
    unsigned long long m0 = __ballot(a[0] > 0);
    unsigned long long m1 = __ballot(a[1] > 0);
    unsigned long long m2 = __ballot(a[2] > 0);
    unsigned long long m3 = __ballot(a[3] > 0);
    if (lane < 4) {
      unsigned long long v = lane == 0 ? m0 : lane == 1 ? m1 : lane == 2 ? m2 : m3;
      bits[(size_t)blk * 4 + lane] = v;
    }
  }
}

// ---------------- Kernel 1: h = X @ W -> hB blocked layout, s1, U=exp(s2), V=exp(.01 s2)
// hB element index for h[i][f]: ((i>>5)*128 + f)*32 + ((i>>3)&3)*8 + (i&7)
// so a B-fragment wave-load (lanes = (f16, kq)) is 1KB contiguous.
__global__ __launch_bounds__(256)
void k1_hw(const float* __restrict__ inp, const float* __restrict__ W,
           const float* __restrict__ a, ushort_t* __restrict__ hB,
           float* __restrict__ s1g, float* __restrict__ Ug, float* __restrict__ Vg)
{
  __shared__ float Wl[FF * FF];     // 64 KB
  __shared__ float il[32 * 129];    // padded, ~16 KB
  __shared__ float red1[32 * 8];
  __shared__ float red2[32 * 8];
  const int t = threadIdx.x;
  const int ib = blockIdx.x * 32;

  {
    const float4* Ws = (const float4*)W;
    float4* Wd = (float4*)Wl;
#pragma unroll
    for (int q = 0; q < 16; ++q) Wd[t + 256 * q] = Ws[t + 256 * q];
  }
#pragma unroll
  for (int q = 0; q < 4; ++q) {
    int idx = t + 256 * q;
    int r = idx >> 5, c4 = idx & 31;
    float4 v = ((const float4*)(inp + (size_t)(ib + r) * FF))[c4];
    float* dst = &il[r * 129 + c4 * 4];
    dst[0] = v.x; dst[1] = v.y; dst[2] = v.z; dst[3] = v.w;
  }
  __syncthreads();

  const int r = t & 31;
  const int c0 = (t >> 5) * 16;
  float acc[16];
#pragma unroll
  for (int j = 0; j < 16; ++j) acc[j] = 0.f;

#pragma unroll 4
  for (int k = 0; k < FF; ++k) {
    float iv = il[r * 129 + k];
    const float4* wrow = (const float4*)&Wl[k * FF + c0];
    float4 w0 = wrow[0], w1 = wrow[1], w2 = wrow[2], w3 = wrow[3];
    acc[0]  += iv * w0.x; acc[1]  += iv * w0.y; acc[2]  += iv * w0.z; acc[3]  += iv * w0.w;
    acc[4]  += iv * w1.x; acc[5]  += iv * w1.y; acc[6]  += iv * w1.z; acc[7]  += iv * w1.w;
    acc[8]  += iv * w2.x; acc[9]  += iv * w2.y; acc[10] += iv * w2.z; acc[11] += iv * w2.w;
    acc[12] += iv * w3.x; acc[13] += iv * w3.y; acc[14] += iv * w3.z; acc[15] += iv * w3.w;
  }

  float ps1 = 0.f, ps2 = 0.f;
#pragma unroll
  for (int q = 0; q < 4; ++q) {
    float4 a1v = *(const float4*)(a + c0 + 4 * q);
    float4 a2v = *(const float4*)(a + FF + c0 + 4 * q);
    ps1 += acc[4*q+0]*a1v.x + acc[4*q+1]*a1v.y + acc[4*q+2]*a1v.z + acc[4*q+3]*a1v.w;
    ps2 += acc[4*q+0]*a2v.x + acc[4*q+1]*a2v.y + acc[4*q+2]*a2v.z + acc[4*q+3]*a2v.w;
  }
  red1[r * 8 + (t >> 5)] = ps1;
  red2[r * 8 + (t >> 5)] = ps2;

#pragma unroll
  for (int j = 0; j < 16; ++j) {
    unsigned b = __float_as_uint(acc[j]);
    hB[((size_t)blockIdx.x * 128 + (c0 + j)) * 32 + ((r >> 3) & 3) * 8 + (r & 7)] =
        (ushort_t)((b + 0x8000u) >> 16);
  }
  __syncthreads();
  if (t < 32) {
    float s1 = 0.f, s2 = 0.f;
#pragma unroll
    for (int g2 = 0; g2 < 8; ++g2) { s1 += red1[t * 8 + g2]; s2 += red2[t * 8 + g2]; }
    s1g[ib + t] = s1;
    Ug[ib + t] = expf(s2);
    Vg[ib + t] = expf(0.01f * s2);
  }
}

// ---------------- Kernel 3: fused masked-softmax @ h
// Grid 512 blocks x 512 threads (8 waves). Block owns 16 output rows, all j, all f.
// j in 8 windows of 1024. Per window: wave w stages rows 2w,2w+1 of the w-tile
// (bits -> gates, U/V -> values) into XOR-swizzled LDS (double-buffered, one
// lgkm-only barrier per window, loads issued before / writes after the MFMA phase).
// MFMA phase: wave w covers f-slice [16w,16w+16): af from LDS (shared), bf from
// hB via 1KB-contiguous L2-resident loads. z via ones-MFMA (redundant per wave).
__global__ __launch_bounds__(512, 4)
void k3_attn(const unsigned long long* __restrict__ bits, const float* __restrict__ s1g,
             const float* __restrict__ Ug, const float* __restrict__ Vg,
             const ushort_t* __restrict__ hB, float* __restrict__ out)
{
  __shared__ ushort_t wtile[2][16][1024];   // 64 KB
  __shared__ float zL[16];

  const int t = threadIdx.x;
  const int lane = t & 63, w = t >> 6;
  const int rowl = lane & 15, kq = lane >> 4;
  const int rb = blockIdx.x * 16;
  const int r0 = 2 * w, r1 = 2 * w + 1;

  // per-row softmax factorization: w[i][j] = adj ? (U_j>E_i ? P_i*U_j : Q_i*V_j) : 0
  // with shift m_i = leaky(s1_i) + 24 (upper bound of row max; shift-invariant)
  const float s1a = s1g[rb + r0];
  const float s1b = s1g[rb + r1];
  const float la = s1a > 0.f ? s1a : 0.01f * s1a;
  const float lb = s1b > 0.f ? s1b : 0.01f * s1b;
  const float Pa = expf(s1a - la - 24.f), Qa = expf(0.01f * s1a - la - 24.f), Ea = expf(-s1a);
  const float Pb = expf(s1b - lb - 24.f), Qb = expf(0.01f * s1b - lb - 24.f), Eb = expf(-s1b);

  f32x4 acc, acc9;
  acc[0] = 0.f; acc[1] = 0.f; acc[2] = 0.f; acc[3] = 0.f;
  acc9[0] = 0.f; acc9[1] = 0.f; acc9[2] = 0.f; acc9[3] = 0.f;

  union { unsigned u[4]; s16x8 v; } onesu;
  onesu.u[0] = 0x3F803F80u; onesu.u[1] = 0x3F803F80u;
  onesu.u[2] = 0x3F803F80u; onesu.u[3] = 0x3F803F80u;
  const s16x8 ones = onesu.v;

  float4 Uq[4], Vq[4];
  u64x2 Ga[4], Gb[4], Gc[4], Gd[4];   // r0 words {0,1},{2,3}; r1 words {0,1},{2,3}

  auto stage_load = [&](int win) {
    const int jw = win * 1024;
    const unsigned long long* bp0 = bits + (size_t)(rb + r0) * 128 + (jw >> 6);
    const unsigned long long* bp1 = bits + (size_t)(rb + r1) * 128 + (jw >> 6);
#pragma unroll
    for (int q = 0; q < 4; ++q) {
      Uq[q] = *(const float4*)(Ug + jw + q * 256 + lane * 4);
      Vq[q] = *(const float4*)(Vg + jw + q * 256 + lane * 4);
      Ga[q] = *(const u64x2*)(bp0 + q * 4);
      Gb[q] = *(const u64x2*)(bp0 + q * 4 + 2);
      Gc[q] = *(const u64x2*)(bp1 + q * 4);
      Gd[q] = *(const u64x2*)(bp1 + q * 4 + 2);
    }
  };

  auto stage_write = [&](int tb) {
    char* base0 = (char*)wtile + tb * 32768 + r0 * 2048;
    char* base1 = (char*)wtile + tb * 32768 + r1 * 2048;
    const int sw0 = (r0 & 7) << 4, sw1 = (r1 & 7) << 4;
#pragma unroll
    for (int q = 0; q < 4; ++q) {
      {
        float w0 = ((Ga[q][0] >> lane) & 1) ? (Uq[q].x > Ea ? Pa * Uq[q].x : Qa * Vq[q].x) : 0.f;
        float w1 = ((Ga[q][1] >> lane) & 1) ? (Uq[q].y > Ea ? Pa * Uq[q].y : Qa * Vq[q].y) : 0.f;
        float w2 = ((Gb[q][0] >> lane) & 1) ? (Uq[q].z > Ea ? Pa * Uq[q].z : Qa * Vq[q].z) : 0.f;
        float w3 = ((Gb[q][1] >> lane) & 1) ? (Uq[q].w > Ea ? Pa * Uq[q].w : Qa * Vq[q].w) : 0.f;
        unsigned p0 = ((__float_as_uint(w0) + 0x8000u) >> 16) | ((__float_as_uint(w1) + 0x8000u) & 0xFFFF0000u);
        unsigned p1 = ((__float_as_uint(w2) + 0x8000u) >> 16) | ((__float_as_uint(w3) + 0x8000u) & 0xFFFF0000u);
        *(uint2*)(base0 + ((q * 512 + lane * 8) ^ sw0)) = make_uint2(p0, p1);
      }
      {
        float w0 = ((Gc[q][0] >> lane) & 1) ? (Uq[q].x > Eb ? Pb * Uq[q].x : Qb * Vq[q].x) : 0.f;
        float w1 = ((Gc[q][1] >> lane) & 1) ? (Uq[q].y > Eb ? Pb * Uq[q].y : Qb * Vq[q].y) : 0.f;
        float w2 = ((Gd[q][0] >> lane) & 1) ? (Uq[q].z > Eb ? Pb * Uq[q].z : Qb * Vq[q].z) : 0.f;
        float w3 = ((Gd[q][1] >> lane) & 1) ? (Uq[q].w > Eb ? Pb * Uq[q].w : Qb * Vq[q].w) : 0.f;
        unsigned p0 = ((__float_as_uint(w0) + 0x8000u) >> 16) | ((__float_as_uint(w1) + 0x8000u) & 0xFFFF0000u);
        unsigned p1 = ((__float_as_uint(w2) + 0x8000u) >> 16) | ((__float_as_uint(w3) + 0x8000u) & 0xFFFF0000u);
        *(uint2*)(base1 + ((q * 512 + lane * 8) ^ sw1)) = make_uint2(p0, p1);
      }
    }
  };

  stage_load(0);
  stage_write(0);
  block_sync_lds();

  for (int win = 0; win < 8; ++win) {
    if (win < 7) stage_load(win + 1);            // issue-early (T14)
    const char* wbuf = (const char*)wtile + (win & 1) * 32768;
    const ushort_t* hp = hB + (size_t)(win * 32) * 4096 + (w * 16 + rowl) * 32 + kq * 8;
#pragma unroll 8
    for (int kc = 0; kc < 32; ++kc) {
      const s16x8 af = *(const s16x8*)(wbuf + rowl * 2048 + (((kc * 4 + kq) ^ (rowl & 7)) << 4));
      const s16x8 bf = *(const s16x8*)(hp + (size_t)kc * 4096);
      acc  = __builtin_amdgcn_mfma_f32_16x16x32_bf16(af, bf,   acc,  0, 0, 0);
      acc9 = __builtin_amdgcn_mfma_f32_16x16x32_bf16(af, ones, acc9, 0, 0, 0);
    }
    if (win < 7) stage_write((win + 1) & 1);     // write-late (after MFMA phase)
    block_sync_lds();
  }

  // z (row sums) identical in every wave's acc9; wave 0 publishes.
  if (w == 0 && rowl == 0) {
#pragma unroll
    for (int r2 = 0; r2 < 4; ++r2) zL[kq * 4 + r2] = acc9[r2];
  }
  __syncthreads();

#pragma unroll
  for (int r2 = 0; r2 < 4; ++r2) {
    const int row = kq * 4 + r2;                 // C/D: col=lane&15, row=(lane>>4)*4+reg
    out[(size_t)(rb + row) * FF + w * 16 + rowl] = acc[r2] * (1.f / zL[row]);
  }
}

extern "C" void kernel_launch(void* const* d_in, const int* in_sizes, int n_in,
                              void* d_out, int out_size, void* d_ws, size_t ws_size,
                              hipStream_t stream)
{
  const float* inp = (const float*)d_in[0];
  const int* adj   = (const int*)d_in[1];
  const float* W   = (const float*)d_in[2];
  const float* a   = (const float*)d_in[3];
  float* out = (float*)d_out;

  char* ws = (char*)d_ws;
  ushort_t* hB = (ushort_t*)ws;                                         // 2 MB
  float* s1g = (float*)(ws + (size_t)(2u << 20));                       // 32 KB
  float* Ug  = (float*)(ws + (size_t)(2u << 20) + (32u << 10));         // 32 KB
  float* Vg  = (float*)(ws + (size_t)(2u << 20) + (64u << 10));         // 32 KB
  unsigned long long* bits = (unsigned long long*)(ws + (size_t)(3u << 20)); // 8 MB

  hipLaunchKernelGGL(k0_pack, dim3(2048), dim3(256), 0, stream, adj, bits);
  hipLaunchKernelGGL(k1_hw, dim3(256), dim3(256), 0, stream, inp, W, a, hB, s1g, Ug, Vg);
  hipLaunchKernelGGL(k3_attn, dim3(512), dim3(512), 0, stream, bits, s1g, Ug, Vg, hB, out);
}

// Round 9
// 469.156 us; speedup vs baseline: 1.1192x; 1.1192x over previous
//
#include <hip/hip_runtime.h>
#include <hip/hip_bf16.h>

#define NN 8192
#define FF 128

typedef unsigned short ushort_t;
typedef __attribute__((ext_vector_type(4))) float f32x4;
typedef __attribute__((ext_vector_type(4))) int i32x4;
typedef __attribute__((ext_vector_type(8))) short s16x8;
typedef __attribute__((ext_vector_type(2))) unsigned long long u64x2;

__device__ __forceinline__ void block_sync_lds() {
  // wait LDS ops only, do NOT drain vmcnt -> global prefetch survives the barrier
  asm volatile("s_waitcnt lgkmcnt(0)\n\ts_barrier" ::: "memory");
}

// ---------------- Kernel 0: bit-pack adj (256 MB -> 8 MB), pure streaming.
// Bit-plane layout: for each 256-int block b, word (b*4+m) bit l <-> adj[b*256 + l*4 + m].
__global__ __launch_bounds__(256)
void k0_pack(const int* __restrict__ adj, unsigned long long* __restrict__ bits)
{
  const int lane = threadIdx.x & 63;
  const int wid = (blockIdx.x * 256 + threadIdx.x) >> 6;   // 8192 waves
  for (int blk = wid; blk < (NN / 256) * NN; blk += 8192) {
    const i32x4 a = *((const i32x4*)adj + (size_t)blk * 64 + lane);   // 1KB contiguous per wave
    unsigned long long m0 = __ballot(a[0] > 0);
    unsigned long long m1 = __ballot(a[1] > 0);
    unsigned long long m2 = __ballot(a[2] > 0);
    unsigned long long m3 = __ballot(a[3] > 0);
    if (lane < 4) {
      unsigned long long v = lane == 0 ? m0 : lane == 1 ? m1 : lane == 2 ? m2 : m3;
      bits[(size_t)blk * 4 + lane] = v;
    }
  }
}

// ---------------- Kernel 1: h = X @ W -> hB blocked layout, s1, U=exp(s2), V=exp(.01 s2)
// hB element index for h[i][f]: ((i>>5)*128 + f)*32 + ((i>>3)&3)*8 + (i&7)
// so a B-fragment wave-load (lanes = (f16, kq)) is 1KB contiguous.
__global__ __launch_bounds__(256)
void k1_hw(const float* __restrict__ inp, const float* __restrict__ W,
           const float* __restrict__ a, ushort_t* __restrict__ hB,
           float* __restrict__ s1g, float* __restrict__ Ug, float* __restrict__ Vg)
{
  __shared__ float Wl[FF * FF];     // 64 KB
  __shared__ float il[32 * 129];    // padded, ~16 KB
  __shared__ float red1[32 * 8];
  __shared__ float red2[32 * 8];
  const int t = threadIdx.x;
  const int ib = blockIdx.x * 32;

  {
    const float4* Ws = (const float4*)W;
    float4* Wd = (float4*)Wl;
#pragma unroll
    for (int q = 0; q < 16; ++q) Wd[t + 256 * q] = Ws[t + 256 * q];
  }
#pragma unroll
  for (int q = 0; q < 4; ++q) {
    int idx = t + 256 * q;
    int r = idx >> 5, c4 = idx & 31;
    float4 v = ((const float4*)(inp + (size_t)(ib + r) * FF))[c4];
    float* dst = &il[r * 129 + c4 * 4];
    dst[0] = v.x; dst[1] = v.y; dst[2] = v.z; dst[3] = v.w;
  }
  __syncthreads();

  const int r = t & 31;
  const int c0 = (t >> 5) * 16;
  float acc[16];
#pragma unroll
  for (int j = 0; j < 16; ++j) acc[j] = 0.f;

#pragma unroll 4
  for (int k = 0; k < FF; ++k) {
    float iv = il[r * 129 + k];
    const float4* wrow = (const float4*)&Wl[k * FF + c0];
    float4 w0 = wrow[0], w1 = wrow[1], w2 = wrow[2], w3 = wrow[3];
    acc[0]  += iv * w0.x; acc[1]  += iv * w0.y; acc[2]  += iv * w0.z; acc[3]  += iv * w0.w;
    acc[4]  += iv * w1.x; acc[5]  += iv * w1.y; acc[6]  += iv * w1.z; acc[7]  += iv * w1.w;
    acc[8]  += iv * w2.x; acc[9]  += iv * w2.y; acc[10] += iv * w2.z; acc[11] += iv * w2.w;
    acc[12] += iv * w3.x; acc[13] += iv * w3.y; acc[14] += iv * w3.z; acc[15] += iv * w3.w;
  }

  float ps1 = 0.f, ps2 = 0.f;
#pragma unroll
  for (int q = 0; q < 4; ++q) {
    float4 a1v = *(const float4*)(a + c0 + 4 * q);
    float4 a2v = *(const float4*)(a + FF + c0 + 4 * q);
    ps1 += acc[4*q+0]*a1v.x + acc[4*q+1]*a1v.y + acc[4*q+2]*a1v.z + acc[4*q+3]*a1v.w;
    ps2 += acc[4*q+0]*a2v.x + acc[4*q+1]*a2v.y + acc[4*q+2]*a2v.z + acc[4*q+3]*a2v.w;
  }
  red1[r * 8 + (t >> 5)] = ps1;
  red2[r * 8 + (t >> 5)] = ps2;

#pragma unroll
  for (int j = 0; j < 16; ++j) {
    unsigned b = __float_as_uint(acc[j]);
    hB[((size_t)blockIdx.x * 128 + (c0 + j)) * 32 + ((r >> 3) & 3) * 8 + (r & 7)] =
        (ushort_t)((b + 0x8000u) >> 16);
  }
  __syncthreads();
  if (t < 32) {
    float s1 = 0.f, s2 = 0.f;
#pragma unroll
    for (int g2 = 0; g2 < 8; ++g2) { s1 += red1[t * 8 + g2]; s2 += red2[t * 8 + g2]; }
    s1g[ib + t] = s1;
    Ug[ib + t] = expf(s2);
    Vg[ib + t] = expf(0.01f * s2);
  }
}

// ---------------- Kernel 3: fused masked-softmax @ h
// Grid 512 blocks x 512 threads (8 waves). Block owns 16 output rows, all j, all f.
// j in 8 windows of 1024. Per window: wave w stages rows 2w,2w+1 of the w-tile
// into XOR-swizzled LDS (double-buffered, one lgkm-only barrier per window,
// U/V prefetched issue-early; bits read inline at write time - L1/L2 hot, 16KB/block).
// MFMA phase: wave w covers f-slice [16w,16w+16): af from LDS (shared), bf from
// hB via 1KB-contiguous L2-resident loads. z via ones-MFMA on wave 0 only.
// NOTE: no second __launch_bounds__ arg - (512,4) was interpreted as 4 blocks/CU
// -> 64-VGPR cap -> massive scratch spills (R6: WRITE_SIZE 80MB vs 4MB out).
__global__ __launch_bounds__(512)
void k3_attn(const unsigned long long* __restrict__ bits, const float* __restrict__ s1g,
             const float* __restrict__ Ug, const float* __restrict__ Vg,
             const ushort_t* __restrict__ hB, float* __restrict__ out)
{
  __shared__ ushort_t wtile[2][16][1024];   // 64 KB
  __shared__ float zL[16];

  const int t = threadIdx.x;
  const int lane = t & 63, w = t >> 6;
  const int rowl = lane & 15, kq = lane >> 4;
  const int rb = blockIdx.x * 16;
  const int r0 = 2 * w, r1 = 2 * w + 1;

  // per-row softmax factorization: w[i][j] = adj ? (U_j>E_i ? P_i*U_j : Q_i*V_j) : 0
  // with shift m_i = leaky(s1_i) + 24 (upper bound of row max; shift-invariant)
  const float s1a = s1g[rb + r0];
  const float s1b = s1g[rb + r1];
  const float la = s1a > 0.f ? s1a : 0.01f * s1a;
  const float lb = s1b > 0.f ? s1b : 0.01f * s1b;
  const float Pa = expf(s1a - la - 24.f), Qa = expf(0.01f * s1a - la - 24.f), Ea = expf(-s1a);
  const float Pb = expf(s1b - lb - 24.f), Qb = expf(0.01f * s1b - lb - 24.f), Eb = expf(-s1b);

  f32x4 acc, acc9;
  acc[0] = 0.f; acc[1] = 0.f; acc[2] = 0.f; acc[3] = 0.f;
  acc9[0] = 0.f; acc9[1] = 0.f; acc9[2] = 0.f; acc9[3] = 0.f;

  union { unsigned u[4]; s16x8 v; } onesu;
  onesu.u[0] = 0x3F803F80u; onesu.u[1] = 0x3F803F80u;
  onesu.u[2] = 0x3F803F80u; onesu.u[3] = 0x3F803F80u;
  const s16x8 ones = onesu.v;

  float4 Uq[4], Vq[4];   // only U/V prefetched in registers (32 VGPR)

  auto stage_load = [&](int win) {
    const int jw = win * 1024;
#pragma unroll
    for (int q = 0; q < 4; ++q) {
      Uq[q] = *(const float4*)(Ug + jw + q * 256 + lane * 4);
      Vq[q] = *(const float4*)(Vg + jw + q * 256 + lane * 4);
    }
  };

  auto stage_write = [&](int tb, int win) {
    const int jw = win * 1024;
    const unsigned long long* bp0 = bits + (size_t)(rb + r0) * 128 + (jw >> 6);
    const unsigned long long* bp1 = bits + (size_t)(rb + r1) * 128 + (jw >> 6);
    char* base0 = (char*)wtile + tb * 32768 + r0 * 2048;
    char* base1 = (char*)wtile + tb * 32768 + r1 * 2048;
    const int sw0 = (r0 & 7) << 4, sw1 = (r1 & 7) << 4;
#pragma unroll
    for (int q = 0; q < 4; ++q) {
      const u64x2 Ga = *(const u64x2*)(bp0 + q * 4);       // uniform-addr broadcast loads
      const u64x2 Gb = *(const u64x2*)(bp0 + q * 4 + 2);   // (bits slice is L1/L2-hot)
      const u64x2 Gc = *(const u64x2*)(bp1 + q * 4);
      const u64x2 Gd = *(const u64x2*)(bp1 + q * 4 + 2);
      {
        float w0 = ((Ga[0] >> lane) & 1) ? (Uq[q].x > Ea ? Pa * Uq[q].x : Qa * Vq[q].x) : 0.f;
        float w1 = ((Ga[1] >> lane) & 1) ? (Uq[q].y > Ea ? Pa * Uq[q].y : Qa * Vq[q].y) : 0.f;
        float w2 = ((Gb[0] >> lane) & 1) ? (Uq[q].z > Ea ? Pa * Uq[q].z : Qa * Vq[q].z) : 0.f;
        float w3 = ((Gb[1] >> lane) & 1) ? (Uq[q].w > Ea ? Pa * Uq[q].w : Qa * Vq[q].w) : 0.f;
        unsigned p0 = ((__float_as_uint(w0) + 0x8000u) >> 16) | ((__float_as_uint(w1) + 0x8000u) & 0xFFFF0000u);
        unsigned p1 = ((__float_as_uint(w2) + 0x8000u) >> 16) | ((__float_as_uint(w3) + 0x8000u) & 0xFFFF0000u);
        *(uint2*)(base0 + ((q * 512 + lane * 8) ^ sw0)) = make_uint2(p0, p1);
      }
      {
        float w0 = ((Gc[0] >> lane) & 1) ? (Uq[q].x > Eb ? Pb * Uq[q].x : Qb * Vq[q].x) : 0.f;
        float w1 = ((Gc[1] >> lane) & 1) ? (Uq[q].y > Eb ? Pb * Uq[q].y : Qb * Vq[q].y) : 0.f;
        float w2 = ((Gd[0] >> lane) & 1) ? (Uq[q].z > Eb ? Pb * Uq[q].z : Qb * Vq[q].z) : 0.f;
        float w3 = ((Gd[1] >> lane) & 1) ? (Uq[q].w > Eb ? Pb * Uq[q].w : Qb * Vq[q].w) : 0.f;
        unsigned p0 = ((__float_as_uint(w0) + 0x8000u) >> 16) | ((__float_as_uint(w1) + 0x8000u) & 0xFFFF0000u);
        unsigned p1 = ((__float_as_uint(w2) + 0x8000u) >> 16) | ((__float_as_uint(w3) + 0x8000u) & 0xFFFF0000u);
        *(uint2*)(base1 + ((q * 512 + lane * 8) ^ sw1)) = make_uint2(p0, p1);
      }
    }
  };

  stage_load(0);
  stage_write(0, 0);
  block_sync_lds();

  for (int win = 0; win < 8; ++win) {
    if (win < 7) stage_load(win + 1);            // issue-early (T14)
    const char* wbuf = (const char*)wtile + (win & 1) * 32768;
    const ushort_t* hp = hB + (size_t)(win * 32) * 4096 + (w * 16 + rowl) * 32 + kq * 8;
#pragma unroll 8
    for (int kc = 0; kc < 32; ++kc) {
      const s16x8 af = *(const s16x8*)(wbuf + rowl * 2048 + (((kc * 4 + kq) ^ (rowl & 7)) << 4));
      const s16x8 bf = *(const s16x8*)(hp + (size_t)kc * 4096);
      acc = __builtin_amdgcn_mfma_f32_16x16x32_bf16(af, bf, acc, 0, 0, 0);
      if (w == 0)  // z identical across waves -> only wave 0 computes it
        acc9 = __builtin_amdgcn_mfma_f32_16x16x32_bf16(af, ones, acc9, 0, 0, 0);
    }
    if (win < 7) stage_write((win + 1) & 1, win + 1);   // write-late (after MFMA phase)
    block_sync_lds();
  }

  // z (row sums) from wave 0's acc9.
  if (w == 0 && rowl == 0) {
#pragma unroll
    for (int r2 = 0; r2 < 4; ++r2) zL[kq * 4 + r2] = acc9[r2];
  }
  __syncthreads();

#pragma unroll
  for (int r2 = 0; r2 < 4; ++r2) {
    const int row = kq * 4 + r2;                 // C/D: col=lane&15, row=(lane>>4)*4+reg
    out[(size_t)(rb + row) * FF + w * 16 + rowl] = acc[r2] * (1.f / zL[row]);
  }
}

extern "C" void kernel_launch(void* const* d_in, const int* in_sizes, int n_in,
                              void* d_out, int out_size, void* d_ws, size_t ws_size,
                              hipStream_t stream)
{
  const float* inp = (const float*)d_in[0];
  const int* adj   = (const int*)d_in[1];
  const float* W   = (const float*)d_in[2];
  const float* a   = (const float*)d_in[3];
  float* out = (float*)d_out;

  char* ws = (char*)d_ws;
  ushort_t* hB = (ushort_t*)ws;                                         // 2 MB
  float* s1g = (float*)(ws + (size_t)(2u << 20));                       // 32 KB
  float* Ug  = (float*)(ws + (size_t)(2u << 20) + (32u << 10));         // 32 KB
  float* Vg  = (float*)(ws + (size_t)(2u << 20) + (64u << 10));         // 32 KB
  unsigned long long* bits = (unsigned long long*)(ws + (size_t)(3u << 20)); // 8 MB

  hipLaunchKernelGGL(k0_pack, dim3(2048), dim3(256), 0, stream, adj, bits);
  hipLaunchKernelGGL(k1_hw, dim3(256), dim3(256), 0, stream, inp, W, a, hB, s1g, Ug, Vg);
  hipLaunchKernelGGL(k3_attn, dim3(512), dim3(512), 0, stream, bits, s1g, Ug, Vg, hB, out);
}